// Round 2
// baseline (670.279 us; speedup 1.0000x reference)
//
#include <hip/hip_runtime.h>

#define VOCAB 65536
#define NELEM 4194304      // 256*16*32*32
#define BHW   262144       // 256*1024

__device__ __forceinline__ double cubic_d(double t) {
  const double a = -0.75;
  t = fabs(t);
  if (t <= 1.0) return ((a + 2.0) * t - (a + 3.0)) * t * t + 1.0;
  if (t < 2.0)  return a * (((t - 5.0) * t + 8.0) * t - 4.0);
  return 0.0;
}

// ---------- quantize for pn < 32: block per image, cooperative f64 cell sums ----------
template<int PN>
__global__ __launch_bounds__(256) void quantize_small(
    const float* __restrict__ f, const float* __restrict__ fhi,
    const float* __restrict__ flo, int* __restrict__ idxbuf,
    float* __restrict__ hist, int si)
{
  constexpr int S = 32 / PN;
  constexpr int CELLS = PN * PN;
  constexpr int TOT = 16 * CELLS;
  __shared__ double cellsum[16][CELLS];
  int b = blockIdx.x;
  int t = threadIdx.x;
  size_t base = (size_t)b * 16384;

  if (TOT >= 256) {
    constexpr int R = (TOT + 255) / 256;
    for (int k = 0; k < R; ++k) {
      int p = t + 256 * k;
      if (p < TOT) {
        int c = p / CELLS, cell = p % CELLS;
        int i = cell / PN, j = cell % PN;
        size_t o0 = base + (size_t)c * 1024 + (size_t)(i * S) * 32 + j * S;
        double s = 0.0;
        for (int dy = 0; dy < S; ++dy)
          for (int dx = 0; dx < S; ++dx) {
            size_t o = o0 + (size_t)dy * 32 + dx;
            s += (double)f[o] - (double)fhi[o] - (double)flo[o];
          }
        cellsum[c][cell] = s;
      }
    }
  } else {
    constexpr int G = 256 / TOT;   // threads per (c,cell); G in {16,4}
    int p = t / G, sub = t % G;
    int c = p / CELLS, cell = p % CELLS;
    int i = cell / PN, j = cell % PN;
    size_t o0 = base + (size_t)c * 1024 + (size_t)(i * S) * 32 + j * S;
    double s = 0.0;
    for (int e = sub; e < S * S; e += G) {
      int dy = e / S, dx = e % S;
      size_t o = o0 + (size_t)dy * 32 + dx;
      s += (double)f[o] - (double)fhi[o] - (double)flo[o];
    }
    #pragma unroll
    for (int off = G / 2; off > 0; off >>= 1)
      s += __shfl_down(s, off, G);
    if (sub == 0) cellsum[c][cell] = s;
  }
  __syncthreads();
  if (t < CELLS) {
    int idx = 0;
    #pragma unroll
    for (int c = 0; c < 16; ++c)
      if (cellsum[c][t] > 0.0) idx |= (1 << c);   // sign(sum)==sign(mean)
    idxbuf[b * CELLS + t] = idx;
    atomicAdd(&hist[si * VOCAB + idx], 1.0f);
  }
}

// ---------- quantize for pn == 32 (last_direct): per-pixel, f64 ----------
__global__ __launch_bounds__(256) void quantize_last(
    const float* __restrict__ f, const float* __restrict__ fhi,
    const float* __restrict__ flo, int* __restrict__ idxbuf,
    float* __restrict__ hist)
{
  int gid = blockIdx.x * 256 + threadIdx.x;   // 262144 threads
  int b = gid >> 10, pix = gid & 1023;
  size_t o0 = (size_t)b * 16384 + pix;
  int idx = 0;
  #pragma unroll
  for (int c = 0; c < 16; ++c) {
    size_t o = o0 + (size_t)c * 1024;
    double r = (double)f[o] - (double)fhi[o] - (double)flo[o];
    if (r > 0.0) idx |= (1 << c);
  }
  idxbuf[gid] = idx;
  atomicAdd(&hist[5 * VOCAB + idx], 1.0f);
}

// ---------- fused: bicubic-up + phi(conv3x3) + f_hat update + losses, f64 core ----------
// grid = 256 (one block per image), 512 threads: thread = (c = t>>5, y = t&31)
template<int PN>
__global__ __launch_bounds__(512) void fused_scale(
    const float* __restrict__ f, float* __restrict__ fhi, float* __restrict__ flo,
    const int* __restrict__ idxbuf, const float* __restrict__ phi_w,
    const float* __restrict__ phi_b, double* __restrict__ acc,
    int phi_idx, int si)
{
  __shared__ double hup[16][32][33];   // pad 33: row stride 264B -> 2-way max
  __shared__ float wlds[2304];
  __shared__ float bias16[16];
  __shared__ float wM[32][PN == 32 ? 1 : PN];   // dense f32 bicubic matrix row
  __shared__ double red[16];

  int b = blockIdx.x, t = threadIdx.x;
  for (int i = t; i < 2304; i += 512) wlds[i] = phi_w[phi_idx * 2304 + i];
  if (t < 16) bias16[t] = phi_b[phi_idx * 16 + t];
  if constexpr (PN != 32) {
    if (t < 32) {
      #pragma unroll
      for (int q = 0; q < PN; ++q) wM[t][q] = 0.0f;
      double xp = ((double)t + 0.5) * (double)PN / 32.0 - 0.5;
      int x0 = (int)floor(xp);
      for (int k = 0; k < 4; ++k) {
        int j = x0 + k - 1;
        int jc = j < 0 ? 0 : (j > PN - 1 ? PN - 1 : j);
        // f32 accumulation of clamp-merged taps matches reference M build
        wM[t][jc] += (float)cubic_d(xp - (double)j);
      }
    }
  }
  __syncthreads();

  int c = t >> 5;     // channel 0..15
  int y = t & 31;     // row
  const int* ib = idxbuf + (size_t)b * PN * PN;

  // ---- upsample ±1 codes into hup (f64 arithmetic, f32 weights) ----
  if constexpr (PN == 32) {
    #pragma unroll
    for (int x = 0; x < 32; ++x)
      hup[c][y][x] = ((ib[y * 32 + x] >> c) & 1) ? 1.0 : -1.0;
  } else {
    double tmp[PN];
    #pragma unroll
    for (int q = 0; q < PN; ++q) tmp[q] = 0.0;
    #pragma unroll
    for (int r = 0; r < PN; ++r) {
      double w = (double)wM[y][r];
      #pragma unroll
      for (int q = 0; q < PN; ++q) {
        double sg = ((ib[r * PN + q] >> c) & 1) ? 1.0 : -1.0;
        tmp[q] = fma(w, sg, tmp[q]);
      }
    }
    #pragma unroll
    for (int x = 0; x < 32; ++x) {
      double s2 = 0.0;
      #pragma unroll
      for (int q = 0; q < PN; ++q) s2 = fma((double)wM[x][q], tmp[q], s2);
      hup[c][y][x] = s2;
    }
  }
  __syncthreads();

  // ---- conv3x3 over channels (SAME, zero pad), sliding window, f64 ----
  double accx[32];
  #pragma unroll
  for (int x = 0; x < 32; ++x) accx[x] = 0.0;
  for (int ci = 0; ci < 16; ++ci) {
    #pragma unroll
    for (int dy = 0; dy < 3; ++dy) {
      int ry = y + dy - 1;
      if (ry < 0 || ry > 31) continue;
      const float* wr = &wlds[((c * 16 + ci) * 3 + dy) * 3];
      double w0 = wr[0], w1 = wr[1], w2 = wr[2];
      const double* row = &hup[ci][ry][0];
      double prev = 0.0, cur = row[0];
      #pragma unroll
      for (int x = 0; x < 32; ++x) {
        double nxt = (x < 31) ? row[x + 1] : 0.0;
        accx[x] = fma(w0, prev, fma(w1, cur, fma(w2, nxt, accx[x])));
        prev = cur; cur = nxt;
      }
    }
  }

  // ---- phi mix + double-float f_hat update + losses ----
  double mse_loc = 0.0;
  float ent_loc = 0.0f, psum = 0.0f;
  {
    double bco = (double)bias16[c];
    size_t base = (size_t)b * 16384 + (size_t)c * 1024 + (size_t)y * 32;
    #pragma unroll
    for (int x = 0; x < 32; ++x) {
      double h = 0.5 * hup[c][y][x] + 0.5 * (accx[x] + bco);
      double fv = (double)f[base + x];
      double fo = (double)fhi[base + x] + (double)flo[base + x];
      double xr = fv - fo;                 // residual BEFORE update
      double fn = fo + h;
      float hi2 = (float)fn;
      fhi[base + x] = hi2;
      flo[base + x] = (float)(fn - (double)hi2);   // Fast2Sum: exact
      double d = fn - fv;
      mse_loc += d * d;
      float xrf = (float)xr;
      float pr = 1.0f / (1.0f + __expf(400.0f * xrf));  // sigmoid(-400 x)
      ent_loc -= pr * __logf(pr + 1e-5f) + (1.0f - pr) * __logf(1.0f - pr + 1e-5f);
      psum += pr;
    }
  }
  // per-channel p sum: the 32 lanes t>>5==c are contiguous
  #pragma unroll
  for (int off = 16; off > 0; off >>= 1) psum += __shfl_down(psum, off, 32);
  if ((t & 31) == 0) atomicAdd(&acc[si * 18 + 2 + c], (double)psum);
  // block-wide mse/ent
  double ent_d = (double)ent_loc;
  #pragma unroll
  for (int off = 32; off > 0; off >>= 1) {
    mse_loc += __shfl_down(mse_loc, off, 64);
    ent_d   += __shfl_down(ent_d, off, 64);
  }
  int wid = t >> 6;
  if ((t & 63) == 0) { red[wid * 2] = mse_loc; red[wid * 2 + 1] = ent_d; }
  __syncthreads();
  if (t == 0) {
    double m = 0.0, e = 0.0;
    #pragma unroll
    for (int w8 = 0; w8 < 8; ++w8) { m += red[w8 * 2]; e += red[w8 * 2 + 1]; }
    atomicAdd(&acc[si * 18 + 0], m);
    atomicAdd(&acc[si * 18 + 1], e);
  }
}

// ---------- final scalar ----------
__global__ void finalize_total(const double* __restrict__ acc, float* __restrict__ total)
{
  if (threadIdx.x == 0 && blockIdx.x == 0) {
    double vq = 0.0, ent = 0.0;
    for (int si = 0; si < 6; ++si) {
      vq += acc[si * 18 + 0];
      double pse = acc[si * 18 + 1] / (double)BHW;
      double ce = 0.0;
      for (int cc = 0; cc < 16; ++cc) {
        double ap0 = acc[si * 18 + 2 + cc] / (double)BHW;
        double ap1 = 1.0 - ap0;
        ce -= ap0 * log(ap0 + 1e-5) + ap1 * log(ap1 + 1e-5);
      }
      ent += pse - ce;
    }
    *total = (float)(1.25 * vq / ((double)NELEM * 6.0) + (0.1 / 6.0) * ent);
  }
}

extern "C" void kernel_launch(void* const* d_in, const int* in_sizes, int n_in,
                              void* d_out, int out_size, void* d_ws, size_t ws_size,
                              hipStream_t stream)
{
  const float* f     = (const float*)d_in[0];
  const float* phi_w = (const float*)d_in[1];
  const float* phi_b = (const float*)d_in[2];
  float* out   = (float*)d_out;
  float* fhi   = out;                 // [0, 4194304) : f_hat high part (the output)
  float* total = out + NELEM;         // [4194304]
  float* hist  = out + NELEM + 1;     // 6*65536
  double* acc  = (double*)d_ws;                         // 108 doubles
  float*  flo  = (float*)((char*)d_ws + 1024);          // 16.8 MB low part
  int*    idxbuf = (int*)((char*)d_ws + 1024 + (size_t)NELEM * 4);  // 1 MB

  hipMemsetAsync(d_out, 0, (size_t)out_size * sizeof(float), stream);
  hipMemsetAsync(d_ws, 0, 1024 + (size_t)NELEM * 4, stream);

  // PHI_IDX = [0,0,1,2,3,3]
  quantize_small<1><<<256, 256, 0, stream>>>(f, fhi, flo, idxbuf, hist, 0);
  fused_scale<1><<<256, 512, 0, stream>>>(f, fhi, flo, idxbuf, phi_w, phi_b, acc, 0, 0);
  quantize_small<2><<<256, 256, 0, stream>>>(f, fhi, flo, idxbuf, hist, 1);
  fused_scale<2><<<256, 512, 0, stream>>>(f, fhi, flo, idxbuf, phi_w, phi_b, acc, 0, 1);
  quantize_small<4><<<256, 256, 0, stream>>>(f, fhi, flo, idxbuf, hist, 2);
  fused_scale<4><<<256, 512, 0, stream>>>(f, fhi, flo, idxbuf, phi_w, phi_b, acc, 1, 2);
  quantize_small<8><<<256, 256, 0, stream>>>(f, fhi, flo, idxbuf, hist, 3);
  fused_scale<8><<<256, 512, 0, stream>>>(f, fhi, flo, idxbuf, phi_w, phi_b, acc, 2, 3);
  quantize_small<16><<<256, 256, 0, stream>>>(f, fhi, flo, idxbuf, hist, 4);
  fused_scale<16><<<256, 512, 0, stream>>>(f, fhi, flo, idxbuf, phi_w, phi_b, acc, 3, 4);
  quantize_last<<<1024, 256, 0, stream>>>(f, fhi, flo, idxbuf, hist);
  fused_scale<32><<<256, 512, 0, stream>>>(f, fhi, flo, idxbuf, phi_w, phi_b, acc, 3, 5);
  finalize_total<<<1, 64, 0, stream>>>(acc, total);
}

// Round 3
// 482.882 us; speedup vs baseline: 1.3881x; 1.3881x over previous
//
#include <hip/hip_runtime.h>

#define VOCAB 65536
#define NELEM 4194304      // 256*16*32*32
#define BHW   262144       // 256*1024

__device__ __forceinline__ double cubic_d(double t) {
  const double a = -0.75;
  t = fabs(t);
  if (t <= 1.0) return ((a + 2.0) * t - (a + 3.0)) * t * t + 1.0;
  if (t < 2.0)  return a * (((t - 5.0) * t + 8.0) * t - 4.0);
  return 0.0;
}

// One scale, fully in-block. Thread mapping: xh=t&3 (8-x strip), y=(t>>2)&31, g=t>>7
// owns channels 4g..4g+3. fhat[cc][k] = f_hat(c=4g+cc, y, x=8*xh+k) in f64.
template<int PN>
__device__ __forceinline__ void process_scale(
    int si, int phi_idx, bool load_w,
    const float* __restrict__ f, const float* __restrict__ phi_w,
    const float* __restrict__ phi_b, float* __restrict__ hist,
    double* __restrict__ acc, double (&fhat)[4][8],
    double* __restrict__ hupd, float* __restrict__ wlds,
    unsigned* __restrict__ idxL, float* __restrict__ wMb, float* __restrict__ wMT,
    float* __restrict__ bias16,
    int t, int xh, int y, int g, int x0, size_t ibase)
{
  constexpr int CELLS = PN * PN;
  constexpr int S = 32 / PN;
  constexpr int TASKS = 16 * CELLS;

  // ---------- P1: zero idx, (re)load weights, wM, resid -> LDS ----------
  for (int i = t; i < 1024; i += 512) idxL[i] = 0u;
  if (load_w) {
    for (int i = t; i < 2304; i += 512) wlds[i] = phi_w[phi_idx * 2304 + i];
    if (t < 16) bias16[t] = phi_b[phi_idx * 16 + t];
  }
  if constexpr (PN != 32) {
    if (t < 32) {
      #pragma unroll
      for (int q = 0; q < PN; ++q) wMb[t * PN + q] = 0.0f;
      double xp = ((double)t + 0.5) * (double)PN / 32.0 - 0.5;
      int q0 = (int)floor(xp);
      for (int k = 0; k < 4; ++k) {
        int j = q0 + k - 1;
        int jc = j < 0 ? 0 : (j > PN - 1 ? PN - 1 : j);
        wMb[t * PN + jc] += (float)cubic_d(xp - (double)j);   // f32 accumulate == np M build
      }
      #pragma unroll
      for (int q = 0; q < PN; ++q) wMT[q * 32 + t] = wMb[t * PN + q];
    }
    #pragma unroll
    for (int cc = 0; cc < 4; ++cc) {
      int c = 4 * g + cc;
      const float* fp = f + ibase + (size_t)c * 1024 + y * 32 + x0;
      double* hp = hupd + c * 1056 + y * 33 + x0;
      #pragma unroll
      for (int k = 0; k < 8; ++k) hp[k] = (double)fp[k] - fhat[cc][k];
    }
  }
  __syncthreads();

  // ---------- P2: quantize (sign of f64 cell sums) -> idxL ----------
  if constexpr (PN == 32) {
    #pragma unroll
    for (int k = 0; k < 8; ++k) {
      unsigned bb = 0;
      #pragma unroll
      for (int cc = 0; cc < 4; ++cc) {
        double r = (double)f[ibase + (size_t)(4 * g + cc) * 1024 + y * 32 + x0 + k] - fhat[cc][k];
        if (r > 0.0) bb |= (1u << cc);
      }
      if (bb) atomicOr(&idxL[y * 32 + x0 + k], bb << (4 * g));
    }
  } else if constexpr (TASKS >= 512) {
    int j = t % CELLS;                     // constant per thread (CELLS divides 512)
    int i0 = (j / PN) * S, j0 = (j % PN) * S;
    unsigned bits = 0;
    #pragma unroll
    for (int k = 0; k < TASKS / 512; ++k) {
      int c = t / CELLS + k * (512 / CELLS);
      const double* hp = hupd + c * 1056 + i0 * 33 + j0;
      double s = 0.0;
      #pragma unroll
      for (int dy = 0; dy < S; ++dy)
        #pragma unroll
        for (int dx = 0; dx < S; ++dx) s += hp[dy * 33 + dx];
      if (s > 0.0) bits |= (1u << c);
    }
    atomicOr(&idxL[j], bits);
  } else {
    if (t < TASKS) {
      int c = t / CELLS, j = t % CELLS;
      int i0 = (j / PN) * S, j0 = (j % PN) * S;
      const double* hp = hupd + c * 1056 + i0 * 33 + j0;
      double s0 = 0, s1 = 0, s2 = 0, s3 = 0;
      for (int dy = 0; dy < S; ++dy) {
        const double* r = hp + dy * 33;
        for (int dx = 0; dx < S; dx += 4) { s0 += r[dx]; s1 += r[dx + 1]; s2 += r[dx + 2]; s3 += r[dx + 3]; }
      }
      if (((s0 + s1) + (s2 + s3)) > 0.0) atomicOr(&idxL[j], 1u << c);
    }
  }
  __syncthreads();

  // ---------- P3: hist + upsample codes -> hupd ----------
  {
    constexpr int NIDX = (PN == 32) ? 1024 : CELLS;
    for (int j = t; j < NIDX; j += 512)
      atomicAdd(&hist[(size_t)si * VOCAB + idxL[j]], 1.0f);
  }
  {
    int c2 = t >> 5, y2 = t & 31;
    double* hrow = hupd + c2 * 1056 + y2 * 33;
    if constexpr (PN == 32) {
      #pragma unroll
      for (int xi = 0; xi < 32; ++xi) {
        int x = (xi + y2) & 31;            // rotate: conflict-free idxL reads
        hrow[x] = ((idxL[y2 * 32 + x] >> c2) & 1) ? 1.0 : -1.0;
      }
    } else {
      double tmp[PN];
      #pragma unroll
      for (int q = 0; q < PN; ++q) tmp[q] = 0.0;
      #pragma unroll
      for (int r = 0; r < PN; ++r) {
        double w = (double)wMT[r * 32 + y2];   // transposed copy: stride-1 across lanes
        #pragma unroll
        for (int q = 0; q < PN; ++q) {
          double sg = ((idxL[r * PN + q] >> c2) & 1) ? 1.0 : -1.0;
          tmp[q] = fma(w, sg, tmp[q]);
        }
      }
      #pragma unroll
      for (int x = 0; x < 32; ++x) {
        double s2 = 0.0;
        #pragma unroll
        for (int q = 0; q < PN; ++q) s2 = fma((double)wMb[x * PN + q], tmp[q], s2);  // x uniform: broadcast
        hrow[x] = s2;
      }
    }
  }
  __syncthreads();

  // ---------- P4: conv3x3 + phi mix + f_hat update + losses ----------
  double accv[4][8];
  #pragma unroll
  for (int cc = 0; cc < 4; ++cc)
    #pragma unroll
    for (int k = 0; k < 8; ++k) accv[cc][k] = 0.0;

  for (int ci = 0; ci < 16; ++ci) {
    double p[3][10];
    #pragma unroll
    for (int dy = 0; dy < 3; ++dy) {
      int ry = y + dy - 1;
      if (ry < 0 || ry > 31) {
        #pragma unroll
        for (int jj = 0; jj < 10; ++jj) p[dy][jj] = 0.0;
      } else {
        const double* hr = hupd + ci * 1056 + ry * 33;
        #pragma unroll
        for (int jj = 0; jj < 10; ++jj) {
          int xx = x0 - 1 + jj;
          p[dy][jj] = (xx < 0 || xx > 31) ? 0.0 : hr[xx];
        }
      }
    }
    #pragma unroll
    for (int cc = 0; cc < 4; ++cc) {
      const float* wp = wlds + ((4 * g + cc) * 16 + ci) * 9;   // wave-uniform: broadcast
      #pragma unroll
      for (int dy = 0; dy < 3; ++dy) {
        double w0 = (double)wp[dy * 3 + 0];
        double w1 = (double)wp[dy * 3 + 1];
        double w2 = (double)wp[dy * 3 + 2];
        #pragma unroll
        for (int k = 0; k < 8; ++k)
          accv[cc][k] = fma(w0, p[dy][k], fma(w1, p[dy][k + 1], fma(w2, p[dy][k + 2], accv[cc][k])));
      }
    }
  }

  double mse = 0.0;
  float entf = 0.0f;
  float ps0 = 0, ps1 = 0, ps2 = 0, ps3 = 0;
  #pragma unroll
  for (int cc = 0; cc < 4; ++cc) {
    int c = 4 * g + cc;
    double bco = (double)bias16[c];
    const double* hu = hupd + c * 1056 + y * 33 + x0;
    const float* fp = f + ibase + (size_t)c * 1024 + y * 32 + x0;
    float psl = 0.0f;
    #pragma unroll
    for (int k = 0; k < 8; ++k) {
      double h = 0.5 * hu[k] + 0.5 * (accv[cc][k] + bco);
      double fv = (double)fp[k];
      double xr = fv - fhat[cc][k];          // residual BEFORE update
      double fn = fhat[cc][k] + h;
      fhat[cc][k] = fn;
      double d = fn - fv;
      mse += d * d;
      float pr = 1.0f / (1.0f + __expf(400.0f * (float)xr));   // sigmoid(-400 x)
      entf -= pr * __logf(pr + 1e-5f) + (1.0f - pr) * __logf(1.0f - pr + 1e-5f);
      psl += pr;
    }
    if (cc == 0) ps0 = psl; else if (cc == 1) ps1 = psl; else if (cc == 2) ps2 = psl; else ps3 = psl;
  }
  #pragma unroll
  for (int off = 32; off > 0; off >>= 1) {
    mse  += __shfl_down(mse, off);
    entf += __shfl_down(entf, off);
    ps0  += __shfl_down(ps0, off);
    ps1  += __shfl_down(ps1, off);
    ps2  += __shfl_down(ps2, off);
    ps3  += __shfl_down(ps3, off);
  }
  if ((t & 63) == 0) {
    atomicAdd(&acc[si * 18 + 0], mse);
    atomicAdd(&acc[si * 18 + 1], (double)entf);
    atomicAdd(&acc[si * 18 + 2 + 4 * g + 0], (double)ps0);
    atomicAdd(&acc[si * 18 + 2 + 4 * g + 1], (double)ps1);
    atomicAdd(&acc[si * 18 + 2 + 4 * g + 2], (double)ps2);
    atomicAdd(&acc[si * 18 + 2 + 4 * g + 3], (double)ps3);
  }
  __syncthreads();
}

__global__ __launch_bounds__(512) void lfq_all(
    const float* __restrict__ f, const float* __restrict__ phi_w,
    const float* __restrict__ phi_b, float* __restrict__ fhi,
    float* __restrict__ hist, double* __restrict__ acc)
{
  __shared__ double   hupd[16 * 1056];   // 135168 B: resid / upsampled codes
  __shared__ float    wlds[2304];        // conv weights
  __shared__ unsigned idxL[1024];        // codes per cell
  __shared__ float    wMb[512];          // bicubic M, row-major [32][PN]
  __shared__ float    wMT[512];          // transposed [PN][32]
  __shared__ float    bias16[16];

  const int t = threadIdx.x;
  const int xh = t & 3, y = (t >> 2) & 31, g = t >> 7;
  const int x0 = xh * 8;
  const size_t ibase = (size_t)blockIdx.x * 16384;

  double fhat[4][8];
  #pragma unroll
  for (int cc = 0; cc < 4; ++cc)
    #pragma unroll
    for (int k = 0; k < 8; ++k) fhat[cc][k] = 0.0;

  // PHI_IDX = [0,0,1,2,3,3]
  process_scale<1 >(0, 0, true,  f, phi_w, phi_b, hist, acc, fhat, hupd, wlds, idxL, wMb, wMT, bias16, t, xh, y, g, x0, ibase);
  process_scale<2 >(1, 0, false, f, phi_w, phi_b, hist, acc, fhat, hupd, wlds, idxL, wMb, wMT, bias16, t, xh, y, g, x0, ibase);
  process_scale<4 >(2, 1, true,  f, phi_w, phi_b, hist, acc, fhat, hupd, wlds, idxL, wMb, wMT, bias16, t, xh, y, g, x0, ibase);
  process_scale<8 >(3, 2, true,  f, phi_w, phi_b, hist, acc, fhat, hupd, wlds, idxL, wMb, wMT, bias16, t, xh, y, g, x0, ibase);
  process_scale<16>(4, 3, true,  f, phi_w, phi_b, hist, acc, fhat, hupd, wlds, idxL, wMb, wMT, bias16, t, xh, y, g, x0, ibase);
  process_scale<32>(5, 3, false, f, phi_w, phi_b, hist, acc, fhat, hupd, wlds, idxL, wMb, wMT, bias16, t, xh, y, g, x0, ibase);

  #pragma unroll
  for (int cc = 0; cc < 4; ++cc) {
    float* op = fhi + ibase + (size_t)(4 * g + cc) * 1024 + y * 32 + x0;
    #pragma unroll
    for (int k = 0; k < 8; ++k) op[k] = (float)fhat[cc][k];
  }
}

__global__ void finalize_total(const double* __restrict__ acc, float* __restrict__ total)
{
  if (threadIdx.x == 0 && blockIdx.x == 0) {
    double vq = 0.0, ent = 0.0;
    for (int si = 0; si < 6; ++si) {
      vq += acc[si * 18 + 0];
      double pse = acc[si * 18 + 1] / (double)BHW;
      double ce = 0.0;
      for (int cc = 0; cc < 16; ++cc) {
        double ap0 = acc[si * 18 + 2 + cc] / (double)BHW;
        double ap1 = 1.0 - ap0;
        ce -= ap0 * log(ap0 + 1e-5) + ap1 * log(ap1 + 1e-5);
      }
      ent += pse - ce;
    }
    *total = (float)(1.25 * vq / ((double)NELEM * 6.0) + (0.1 / 6.0) * ent);
  }
}

extern "C" void kernel_launch(void* const* d_in, const int* in_sizes, int n_in,
                              void* d_out, int out_size, void* d_ws, size_t ws_size,
                              hipStream_t stream)
{
  const float* f     = (const float*)d_in[0];
  const float* phi_w = (const float*)d_in[1];
  const float* phi_b = (const float*)d_in[2];
  float* out   = (float*)d_out;
  float* fhi   = out;                 // [0, NELEM) — fully overwritten
  float* total = out + NELEM;
  float* hist  = out + NELEM + 1;     // 6*65536
  double* acc  = (double*)d_ws;       // 108 doubles

  // zero only hist+total (fhi fully written by kernel) and the accumulators
  hipMemsetAsync((void*)(out + NELEM), 0, (size_t)(1 + 6 * VOCAB) * sizeof(float), stream);
  hipMemsetAsync(d_ws, 0, 1024, stream);

  lfq_all<<<256, 512, 0, stream>>>(f, phi_w, phi_b, fhi, hist, acc);
  finalize_total<<<1, 64, 0, stream>>>(acc, total);
}

// Round 4
// 388.636 us; speedup vs baseline: 1.7247x; 1.2425x over previous
//
#include <hip/hip_runtime.h>

#define VOCAB 65536
#define NELEM 4194304      // 256*16*32*32
#define BHW   262144       // 256*1024

__device__ __forceinline__ double cubic_d(double t) {
  const double a = -0.75;
  t = fabs(t);
  if (t <= 1.0) return ((a + 2.0) * t - (a + 3.0)) * t * t + 1.0;
  if (t < 2.0)  return a * (((t - 5.0) * t + 8.0) * t - 4.0);
  return 0.0;
}

// thread map (1024 threads): xh=t&3 (8-x strip), y=(t>>2)&31, g=t>>7 (channels 2g,2g+1)
template<int PN>
__device__ __forceinline__ void process_scale(
    int si, int phi_idx, bool load_w,
    const float* __restrict__ phi_w, const float* __restrict__ phi_b,
    float* __restrict__ hist, double* __restrict__ acc,
    const float (&fown)[2][8], double (&fhat)[2][8],
    double* __restrict__ hupd, float* __restrict__ wlds,
    unsigned* __restrict__ idxL, float* __restrict__ wMb, float* __restrict__ wMT,
    float* __restrict__ bias16, double* __restrict__ red,
    int t, int y, int g, int x0)
{
  constexpr int CELLS = PN * PN;
  constexpr int S = 32 / PN;

  // ---------- P0: zero idx, (re)load weights, wM, stage resid ----------
  idxL[t] = 0u;
  if (load_w) {
    for (int i = t; i < 2304; i += 1024) wlds[i] = phi_w[phi_idx * 2304 + i];
    if (t < 16) bias16[t] = phi_b[phi_idx * 16 + t];
  }
  if constexpr (PN != 32) {
    if (t < 32) {
      float wrow[PN];
      #pragma unroll
      for (int q = 0; q < PN; ++q) wrow[q] = 0.0f;
      double xp = ((double)t + 0.5) * (double)PN / 32.0 - 0.5;
      int q0 = (int)floor(xp);
      for (int k = 0; k < 4; ++k) {
        int j = q0 + k - 1;
        int jc = j < 0 ? 0 : (j > PN - 1 ? PN - 1 : j);
        wrow[jc] += (float)cubic_d(xp - (double)j);   // f32 accumulate == np M build
      }
      #pragma unroll
      for (int q = 0; q < PN; ++q) { wMb[t * PN + q] = wrow[q]; wMT[q * 32 + t] = wrow[q]; }
    }
    #pragma unroll
    for (int cc = 0; cc < 2; ++cc) {
      double* hp = hupd + (2 * g + cc) * 1056 + y * 33 + x0;
      #pragma unroll
      for (int k = 0; k < 8; ++k) hp[k] = (double)fown[cc][k] - fhat[cc][k];
    }
  }
  __syncthreads();

  // ---------- P2: quantize (sign of f64 cell sums) -> idxL ----------
  if constexpr (PN == 32) {
    #pragma unroll
    for (int k = 0; k < 8; ++k) {
      unsigned bb = 0;
      #pragma unroll
      for (int cc = 0; cc < 2; ++cc)
        if ((double)fown[cc][k] - fhat[cc][k] > 0.0) bb |= (1u << cc);
      if (bb) atomicOr(&idxL[(x0 + k) * 32 + y], bb << (2 * g));   // transposed layout
    }
  } else if constexpr (PN == 16) {
    int cell = t & 255;
    int i0 = (cell >> 4) * 2, j0 = (cell & 15) * 2;
    unsigned bits = 0;
    #pragma unroll
    for (int k = 0; k < 4; ++k) {
      int c = (t >> 8) + 4 * k;
      const double* hp = hupd + c * 1056 + i0 * 33 + j0;
      double s = hp[0] + hp[1] + hp[33] + hp[34];
      if (s > 0.0) bits |= (1u << c);
    }
    atomicOr(&idxL[cell], bits);
  } else if constexpr (PN == 8) {
    int c = t >> 6, cell = t & 63;
    const double* hp = hupd + c * 1056 + ((cell >> 3) * 4) * 33 + (cell & 7) * 4;
    double s = 0.0;
    #pragma unroll
    for (int dy = 0; dy < 4; ++dy)
      #pragma unroll
      for (int dx = 0; dx < 4; ++dx) s += hp[dy * 33 + dx];
    if (s > 0.0) atomicOr(&idxL[cell], 1u << c);
  } else {   // PN 1,2,4
    constexpr int TASKS = 16 * CELLS;
    constexpr int G = 1024 / TASKS;       // 64, 16, 4
    int p = t / G, sub = t % G;
    int c = p / CELLS, cell = p % CELLS;
    const double* hp = hupd + c * 1056 + ((cell / PN) * S) * 33 + (cell % PN) * S;
    double s = 0.0;
    for (int e = sub; e < S * S; e += G) {
      int dy = e / S, dx = e % S;
      s += hp[dy * 33 + dx];
    }
    #pragma unroll
    for (int off = G / 2; off > 0; off >>= 1) s += __shfl_down(s, off, G);
    if (sub == 0 && s > 0.0) atomicOr(&idxL[cell], 1u << c);
  }
  __syncthreads();

  // ---------- P3: hist + upsample codes -> hupd ----------
  if constexpr (PN == 32) {
    atomicAdd(&hist[5 * VOCAB + idxL[t]], 1.0f);
  } else {
    if (t < CELLS) atomicAdd(&hist[(size_t)si * VOCAB + idxL[t]], 1.0f);
  }
  {
    int c2 = t >> 6, sub = (t >> 5) & 1, y2 = t & 31;
    double* hrow = hupd + c2 * 1056 + y2 * 33;
    if constexpr (PN == 32) {
      #pragma unroll
      for (int xi = 0; xi < 16; ++xi) {
        int x = 16 * sub + xi;
        hrow[x] = ((idxL[x * 32 + y2] >> c2) & 1) ? 1.0 : -1.0;
      }
    } else {
      double tmp[PN];
      #pragma unroll
      for (int q = 0; q < PN; ++q) tmp[q] = 0.0;
      #pragma unroll
      for (int r = 0; r < PN; ++r) {
        double w = (double)wMT[r * 32 + y2];
        #pragma unroll
        for (int q = 0; q < PN; ++q) {
          double sg = ((idxL[r * PN + q] >> c2) & 1) ? 1.0 : -1.0;
          tmp[q] = fma(w, sg, tmp[q]);
        }
      }
      #pragma unroll
      for (int xi = 0; xi < 16; ++xi) {
        int x = 16 * sub + xi;
        double s2 = 0.0;
        #pragma unroll
        for (int q = 0; q < PN; ++q) s2 = fma((double)wMb[x * PN + q], tmp[q], s2);
        hrow[x] = s2;
      }
    }
  }
  __syncthreads();

  // ---------- P4: conv3x3 (row-streamed) + phi mix + f_hat update + losses ----------
  double accv[2][8];
  #pragma unroll
  for (int cc = 0; cc < 2; ++cc)
    #pragma unroll
    for (int k = 0; k < 8; ++k) accv[cc][k] = 0.0;

  for (int ci = 0; ci < 16; ++ci) {
    const double* hbase = hupd + ci * 1056;
    #pragma unroll
    for (int dy = 0; dy < 3; ++dy) {
      int ry = y + dy - 1;
      if (ry < 0 || ry > 31) continue;
      double prow[10];
      const double* hr = hbase + ry * 33;
      #pragma unroll
      for (int jj = 0; jj < 10; ++jj) {
        int xx = x0 - 1 + jj;
        prow[jj] = (xx < 0 || xx > 31) ? 0.0 : hr[xx];
      }
      #pragma unroll
      for (int cc = 0; cc < 2; ++cc) {
        const float* wp = wlds + (((2 * g + cc) * 16 + ci) * 9 + dy * 3);
        double w0 = (double)wp[0], w1 = (double)wp[1], w2 = (double)wp[2];
        #pragma unroll
        for (int k = 0; k < 8; ++k)
          accv[cc][k] = fma(w0, prow[k], fma(w1, prow[k + 1], fma(w2, prow[k + 2], accv[cc][k])));
      }
    }
  }

  double mse = 0.0;
  float entf = 0.0f, ps0 = 0.0f, ps1 = 0.0f;
  #pragma unroll
  for (int cc = 0; cc < 2; ++cc) {
    int c = 2 * g + cc;
    double bco = (double)bias16[c];
    const double* hu = hupd + c * 1056 + y * 33 + x0;
    float psl = 0.0f;
    #pragma unroll
    for (int k = 0; k < 8; ++k) {
      double h = 0.5 * hu[k] + 0.5 * (accv[cc][k] + bco);
      double fv = (double)fown[cc][k];
      double xr = fv - fhat[cc][k];            // residual BEFORE update
      double fn = fhat[cc][k] + h;
      fhat[cc][k] = fn;
      double d = fn - fv;
      mse += d * d;
      float pr = 1.0f / (1.0f + __expf(400.0f * (float)xr));   // sigmoid(-400 x)
      entf -= pr * __logf(pr + 1e-5f) + (1.0f - pr) * __logf(1.0f - pr + 1e-5f);
      psl += pr;
    }
    if (cc == 0) ps0 = psl; else ps1 = psl;
  }
  double ent_d = (double)entf;
  #pragma unroll
  for (int off = 32; off > 0; off >>= 1) {
    mse   += __shfl_down(mse, off);
    ent_d += __shfl_down(ent_d, off);
    ps0   += __shfl_down(ps0, off);
    ps1   += __shfl_down(ps1, off);
  }
  int w = t >> 6;
  if ((t & 63) == 0) {
    red[w * 4 + 0] = mse;
    red[w * 4 + 1] = ent_d;
    red[w * 4 + 2] = (double)ps0;
    red[w * 4 + 3] = (double)ps1;
  }
  __syncthreads();

  // ---------- P5: block totals -> global acc (overlaps next scale's P0) ----------
  if (t == 0) {
    double m = 0.0, e = 0.0;
    #pragma unroll
    for (int ww = 0; ww < 16; ++ww) { m += red[ww * 4]; e += red[ww * 4 + 1]; }
    atomicAdd(&acc[si * 18 + 0], m);
    atomicAdd(&acc[si * 18 + 1], e);
  }
  if (t < 16) {
    int gg = t >> 1, cc = t & 1;
    double p = red[(2 * gg) * 4 + 2 + cc] + red[(2 * gg + 1) * 4 + 2 + cc];
    atomicAdd(&acc[si * 18 + 2 + t], p);
  }
}

__global__ __launch_bounds__(1024, 4) void lfq_all(
    const float* __restrict__ f, const float* __restrict__ phi_w,
    const float* __restrict__ phi_b, float* __restrict__ fhi,
    float* __restrict__ hist, double* __restrict__ acc)
{
  __shared__ double   hupd[16 * 1056];   // 135168 B: resid / upsampled codes
  __shared__ float    wlds[2304];        // conv weights
  __shared__ unsigned idxL[1024];        // codes per cell (transposed for PN=32)
  __shared__ float    wMb[512];          // bicubic M [32][PN]
  __shared__ float    wMT[512];          // transposed [PN][32]
  __shared__ float    bias16[16];
  __shared__ double   red[64];           // 16 waves x 4 slots

  const int t = threadIdx.x;
  const int xh = t & 3, y = (t >> 2) & 31, g = t >> 7;
  const int x0 = xh * 8;
  const size_t ibase = (size_t)blockIdx.x * 16384;

  float fown[2][8];
  double fhat[2][8];
  #pragma unroll
  for (int cc = 0; cc < 2; ++cc) {
    const float* fp = f + ibase + (size_t)(2 * g + cc) * 1024 + y * 32 + x0;
    #pragma unroll
    for (int k = 0; k < 8; ++k) { fown[cc][k] = fp[k]; fhat[cc][k] = 0.0; }
  }

  // PHI_IDX = [0,0,1,2,3,3]
  process_scale<1 >(0, 0, true,  phi_w, phi_b, hist, acc, fown, fhat, hupd, wlds, idxL, wMb, wMT, bias16, red, t, y, g, x0);
  process_scale<2 >(1, 0, false, phi_w, phi_b, hist, acc, fown, fhat, hupd, wlds, idxL, wMb, wMT, bias16, red, t, y, g, x0);
  process_scale<4 >(2, 1, true,  phi_w, phi_b, hist, acc, fown, fhat, hupd, wlds, idxL, wMb, wMT, bias16, red, t, y, g, x0);
  process_scale<8 >(3, 2, true,  phi_w, phi_b, hist, acc, fown, fhat, hupd, wlds, idxL, wMb, wMT, bias16, red, t, y, g, x0);
  process_scale<16>(4, 3, true,  phi_w, phi_b, hist, acc, fown, fhat, hupd, wlds, idxL, wMb, wMT, bias16, red, t, y, g, x0);
  process_scale<32>(5, 3, false, phi_w, phi_b, hist, acc, fown, fhat, hupd, wlds, idxL, wMb, wMT, bias16, red, t, y, g, x0);

  #pragma unroll
  for (int cc = 0; cc < 2; ++cc) {
    float* op = fhi + ibase + (size_t)(2 * g + cc) * 1024 + y * 32 + x0;
    #pragma unroll
    for (int k = 0; k < 8; ++k) op[k] = (float)fhat[cc][k];
  }
}

__global__ void finalize_total(const double* __restrict__ acc, float* __restrict__ total)
{
  if (threadIdx.x == 0 && blockIdx.x == 0) {
    double vq = 0.0, ent = 0.0;
    for (int si = 0; si < 6; ++si) {
      vq += acc[si * 18 + 0];
      double pse = acc[si * 18 + 1] / (double)BHW;
      double ce = 0.0;
      for (int cc = 0; cc < 16; ++cc) {
        double ap0 = acc[si * 18 + 2 + cc] / (double)BHW;
        double ap1 = 1.0 - ap0;
        ce -= ap0 * log(ap0 + 1e-5) + ap1 * log(ap1 + 1e-5);
      }
      ent += pse - ce;
    }
    *total = (float)(1.25 * vq / ((double)NELEM * 6.0) + (0.1 / 6.0) * ent);
  }
}

extern "C" void kernel_launch(void* const* d_in, const int* in_sizes, int n_in,
                              void* d_out, int out_size, void* d_ws, size_t ws_size,
                              hipStream_t stream)
{
  const float* f     = (const float*)d_in[0];
  const float* phi_w = (const float*)d_in[1];
  const float* phi_b = (const float*)d_in[2];
  float* out   = (float*)d_out;
  float* fhi   = out;                 // [0, NELEM) — fully overwritten
  float* total = out + NELEM;
  float* hist  = out + NELEM + 1;     // 6*65536
  double* acc  = (double*)d_ws;       // 108 doubles

  hipMemsetAsync((void*)(out + NELEM), 0, (size_t)(1 + 6 * VOCAB) * sizeof(float), stream);
  hipMemsetAsync(d_ws, 0, 1024, stream);

  lfq_all<<<256, 1024, 0, stream>>>(f, phi_w, phi_b, fhi, hist, acc);
  finalize_total<<<1, 64, 0, stream>>>(acc, total);
}

// Round 5
// 387.271 us; speedup vs baseline: 1.7308x; 1.0035x over previous
//
#include <hip/hip_runtime.h>

#define VOCAB 65536
#define NELEM 4194304      // 256*16*32*32
#define BHW   262144       // 256*1024

__device__ __forceinline__ double cubic_d(double t) {
  const double a = -0.75;
  t = fabs(t);
  if (t <= 1.0) return ((a + 2.0) * t - (a + 3.0)) * t * t + 1.0;
  if (t < 2.0)  return a * (((t - 5.0) * t + 8.0) * t - 4.0);
  return 0.0;
}

// PN=32 idx slot: XOR swizzle -> conflict-free for both writes (fixed y, varying x)
// and reads (fixed x, varying y). Bijective in (x,y).
__device__ __forceinline__ int idx32_slot(int x, int y) { return (x << 5) | ((y ^ x) & 31); }

// thread map (1024 threads): xq=t&7 (4-x strip, x0=4*xq), y=(t>>3)&31, g=t>>8
// owns channels 4g..4g+3. fhat[cc][k] = f_hat(c=4g+cc, y, x=4*xq+k) in f64.
template<int PN>
__device__ __forceinline__ void process_scale(
    int si, int phi_idx, bool load_w,
    const float* __restrict__ phi_w, const float* __restrict__ phi_b,
    float* __restrict__ hist, double* __restrict__ acc,
    const float (&fown)[4][4], double (&fhat)[4][4],
    double* __restrict__ hupd, float* __restrict__ wlds,
    unsigned* __restrict__ idxL, float* __restrict__ wMb, float* __restrict__ wMT,
    float* __restrict__ bias16, double* __restrict__ red,
    int t, int y, int g, int x0)
{
  constexpr int CELLS = PN * PN;
  constexpr int S = 32 / PN;

  // ---------- P0: zero idx, (re)load weights, wM, stage resid ----------
  idxL[t] = 0u;
  if (load_w) {
    for (int i = t; i < 2304; i += 1024) wlds[i] = phi_w[phi_idx * 2304 + i];
    if (t < 16) bias16[t] = phi_b[phi_idx * 16 + t];
  }
  if constexpr (PN != 32) {
    if (t < 32) {
      float wrow[PN];
      #pragma unroll
      for (int q = 0; q < PN; ++q) wrow[q] = 0.0f;
      double xp = ((double)t + 0.5) * (double)PN / 32.0 - 0.5;
      int q0 = (int)floor(xp);
      for (int k = 0; k < 4; ++k) {
        int j = q0 + k - 1;
        int jc = j < 0 ? 0 : (j > PN - 1 ? PN - 1 : j);
        wrow[jc] += (float)cubic_d(xp - (double)j);   // f32 accumulate == np M build
      }
      #pragma unroll
      for (int q = 0; q < PN; ++q) { wMb[t * PN + q] = wrow[q]; wMT[q * 32 + t] = wrow[q]; }
    }
    #pragma unroll
    for (int cc = 0; cc < 4; ++cc) {
      double* hp = hupd + (4 * g + cc) * 1056 + y * 33 + x0;
      #pragma unroll
      for (int k = 0; k < 4; ++k) hp[k] = (double)fown[cc][k] - fhat[cc][k];
    }
  }
  __syncthreads();

  // ---------- P2: quantize (sign of f64 cell sums) -> idxL ----------
  if constexpr (PN == 32) {
    #pragma unroll
    for (int k = 0; k < 4; ++k) {
      unsigned bb = 0;
      #pragma unroll
      for (int cc = 0; cc < 4; ++cc)
        if ((double)fown[cc][k] - fhat[cc][k] > 0.0) bb |= (1u << cc);
      if (bb) atomicOr(&idxL[idx32_slot(x0 + k, y)], bb << (4 * g));
    }
  } else if constexpr (PN == 16) {
    int cell = t & 255;
    int i0 = (cell >> 4) * 2, j0 = (cell & 15) * 2;
    unsigned bits = 0;
    #pragma unroll
    for (int k = 0; k < 4; ++k) {
      int c = (t >> 8) + 4 * k;
      const double* hp = hupd + c * 1056 + i0 * 33 + j0;
      double s = hp[0] + hp[1] + hp[33] + hp[34];
      if (s > 0.0) bits |= (1u << c);
    }
    atomicOr(&idxL[cell], bits);
  } else if constexpr (PN == 8) {
    int c = t >> 6, cell = t & 63;
    const double* hp = hupd + c * 1056 + ((cell >> 3) * 4) * 33 + (cell & 7) * 4;
    double s = 0.0;
    #pragma unroll
    for (int dy = 0; dy < 4; ++dy)
      #pragma unroll
      for (int dx = 0; dx < 4; ++dx) s += hp[dy * 33 + dx];
    if (s > 0.0) atomicOr(&idxL[cell], 1u << c);
  } else {   // PN 1,2,4
    constexpr int TASKS = 16 * CELLS;
    constexpr int G = 1024 / TASKS;       // 64, 16, 4
    int p = t / G, sub = t % G;
    int c = p / CELLS, cell = p % CELLS;
    const double* hp = hupd + c * 1056 + ((cell / PN) * S) * 33 + (cell % PN) * S;
    double s = 0.0;
    for (int e = sub; e < S * S; e += G) {
      int dy = e / S, dx = e % S;
      s += hp[dy * 33 + dx];
    }
    #pragma unroll
    for (int off = G / 2; off > 0; off >>= 1) s += __shfl_down(s, off, G);
    if (sub == 0 && s > 0.0) atomicOr(&idxL[cell], 1u << c);
  }
  __syncthreads();

  // ---------- P3: hist + upsample codes -> hupd ----------
  if constexpr (PN == 32) {
    atomicAdd(&hist[5 * VOCAB + idxL[t]], 1.0f);   // swizzle is bijective
  } else {
    if (t < CELLS) atomicAdd(&hist[(size_t)si * VOCAB + idxL[t]], 1.0f);
  }
  {
    int c2 = t >> 6, sub = (t >> 5) & 1, y2 = t & 31;
    double* hrow = hupd + c2 * 1056 + y2 * 33;
    if constexpr (PN == 32) {
      #pragma unroll
      for (int xi = 0; xi < 16; ++xi) {
        int x = 16 * sub + xi;
        hrow[x] = ((idxL[idx32_slot(x, y2)] >> c2) & 1) ? 1.0 : -1.0;
      }
    } else {
      double tmp[PN];
      #pragma unroll
      for (int q = 0; q < PN; ++q) tmp[q] = 0.0;
      #pragma unroll
      for (int r = 0; r < PN; ++r) {
        double w = (double)wMT[r * 32 + y2];
        #pragma unroll
        for (int q = 0; q < PN; ++q) {
          double sg = ((idxL[r * PN + q] >> c2) & 1) ? 1.0 : -1.0;
          tmp[q] = fma(w, sg, tmp[q]);
        }
      }
      #pragma unroll
      for (int xi = 0; xi < 16; ++xi) {
        int x = 16 * sub + xi;
        double s2 = 0.0;
        #pragma unroll
        for (int q = 0; q < PN; ++q) s2 = fma((double)wMb[x * PN + q], tmp[q], s2);
        hrow[x] = s2;
      }
    }
  }
  __syncthreads();

  // ---------- P4: conv3x3 (row-streamed, 6-wide halo) + phi mix + update + losses ----------
  double accv[4][4];
  #pragma unroll
  for (int cc = 0; cc < 4; ++cc)
    #pragma unroll
    for (int k = 0; k < 4; ++k) accv[cc][k] = 0.0;

  for (int ci = 0; ci < 16; ++ci) {
    const double* hbase = hupd + ci * 1056;
    #pragma unroll
    for (int dy = 0; dy < 3; ++dy) {
      int ry = y + dy - 1;
      if (ry < 0 || ry > 31) continue;
      double prow[6];
      const double* hr = hbase + ry * 33;
      #pragma unroll
      for (int jj = 0; jj < 6; ++jj) {
        int xx = x0 - 1 + jj;
        prow[jj] = (xx < 0 || xx > 31) ? 0.0 : hr[xx];
      }
      #pragma unroll
      for (int cc = 0; cc < 4; ++cc) {
        const float* wp = wlds + (((4 * g + cc) * 16 + ci) * 9 + dy * 3);
        double w0 = (double)wp[0], w1 = (double)wp[1], w2 = (double)wp[2];
        #pragma unroll
        for (int k = 0; k < 4; ++k)
          accv[cc][k] = fma(w0, prow[k], fma(w1, prow[k + 1], fma(w2, prow[k + 2], accv[cc][k])));
      }
    }
  }

  double mse = 0.0;
  float entf = 0.0f;
  float ps[4] = {0.0f, 0.0f, 0.0f, 0.0f};
  #pragma unroll
  for (int cc = 0; cc < 4; ++cc) {
    int c = 4 * g + cc;
    double bco = (double)bias16[c];
    const double* hu = hupd + c * 1056 + y * 33 + x0;
    float psl = 0.0f;
    #pragma unroll
    for (int k = 0; k < 4; ++k) {
      double h = 0.5 * hu[k] + 0.5 * (accv[cc][k] + bco);
      double fv = (double)fown[cc][k];
      double xr = fv - fhat[cc][k];            // residual BEFORE update
      double fn = fhat[cc][k] + h;
      fhat[cc][k] = fn;
      double d = fn - fv;
      mse += d * d;
      float pr = 1.0f / (1.0f + __expf(400.0f * (float)xr));   // sigmoid(-400 x)
      entf -= pr * __logf(pr + 1e-5f) + (1.0f - pr) * __logf(1.0f - pr + 1e-5f);
      psl += pr;
    }
    ps[cc] = psl;
  }
  double ent_d = (double)entf;
  #pragma unroll
  for (int off = 32; off > 0; off >>= 1) {
    mse   += __shfl_down(mse, off);
    ent_d += __shfl_down(ent_d, off);
    ps[0] += __shfl_down(ps[0], off);
    ps[1] += __shfl_down(ps[1], off);
    ps[2] += __shfl_down(ps[2], off);
    ps[3] += __shfl_down(ps[3], off);
  }
  int w = t >> 6;
  if ((t & 63) == 0) {
    red[w * 6 + 0] = mse;
    red[w * 6 + 1] = ent_d;
    red[w * 6 + 2] = (double)ps[0];
    red[w * 6 + 3] = (double)ps[1];
    red[w * 6 + 4] = (double)ps[2];
    red[w * 6 + 5] = (double)ps[3];
  }
  __syncthreads();

  // ---------- P5: block totals -> global acc ----------
  if (t == 0) {
    double m = 0.0, e = 0.0;
    #pragma unroll
    for (int ww = 0; ww < 16; ++ww) { m += red[ww * 6]; e += red[ww * 6 + 1]; }
    atomicAdd(&acc[si * 18 + 0], m);
    atomicAdd(&acc[si * 18 + 1], e);
  }
  if (t < 16) {
    // channel t = 4*gg + cc is produced by waves 4*gg .. 4*gg+3 (4 waves per g)
    int gg = t >> 2, cc = t & 3;
    double p = red[(4 * gg + 0) * 6 + 2 + cc] + red[(4 * gg + 1) * 6 + 2 + cc]
             + red[(4 * gg + 2) * 6 + 2 + cc] + red[(4 * gg + 3) * 6 + 2 + cc];
    atomicAdd(&acc[si * 18 + 2 + t], p);
  }
  __syncthreads();
}

__global__ __launch_bounds__(1024) void lfq_all(
    const float* __restrict__ f, const float* __restrict__ phi_w,
    const float* __restrict__ phi_b, float* __restrict__ fhi,
    float* __restrict__ hist, double* __restrict__ acc)
{
  __shared__ double   hupd[16 * 1056];   // 135168 B: resid / upsampled codes
  __shared__ float    wlds[2304];        // conv weights
  __shared__ unsigned idxL[1024];        // codes per cell (XOR-swizzled for PN=32)
  __shared__ float    wMb[512];          // bicubic M [32][PN]
  __shared__ float    wMT[512];          // transposed [PN][32]
  __shared__ float    bias16[16];
  __shared__ double   red[96];           // 16 waves x 6 slots

  const int t = threadIdx.x;
  const int xq = t & 7, y = (t >> 3) & 31, g = t >> 8;
  const int x0 = xq * 4;
  const size_t ibase = (size_t)blockIdx.x * 16384;

  float fown[4][4];
  double fhat[4][4];
  #pragma unroll
  for (int cc = 0; cc < 4; ++cc) {
    const float* fp = f + ibase + (size_t)(4 * g + cc) * 1024 + y * 32 + x0;
    #pragma unroll
    for (int k = 0; k < 4; ++k) { fown[cc][k] = fp[k]; fhat[cc][k] = 0.0; }
  }

  // PHI_IDX = [0,0,1,2,3,3]
  process_scale<1 >(0, 0, true,  phi_w, phi_b, hist, acc, fown, fhat, hupd, wlds, idxL, wMb, wMT, bias16, red, t, y, g, x0);
  process_scale<2 >(1, 0, false, phi_w, phi_b, hist, acc, fown, fhat, hupd, wlds, idxL, wMb, wMT, bias16, red, t, y, g, x0);
  process_scale<4 >(2, 1, true,  phi_w, phi_b, hist, acc, fown, fhat, hupd, wlds, idxL, wMb, wMT, bias16, red, t, y, g, x0);
  process_scale<8 >(3, 2, true,  phi_w, phi_b, hist, acc, fown, fhat, hupd, wlds, idxL, wMb, wMT, bias16, red, t, y, g, x0);
  process_scale<16>(4, 3, true,  phi_w, phi_b, hist, acc, fown, fhat, hupd, wlds, idxL, wMb, wMT, bias16, red, t, y, g, x0);
  process_scale<32>(5, 3, false, phi_w, phi_b, hist, acc, fown, fhat, hupd, wlds, idxL, wMb, wMT, bias16, red, t, y, g, x0);

  #pragma unroll
  for (int cc = 0; cc < 4; ++cc) {
    float* op = fhi + ibase + (size_t)(4 * g + cc) * 1024 + y * 32 + x0;
    #pragma unroll
    for (int k = 0; k < 4; ++k) op[k] = (float)fhat[cc][k];
  }
}

__global__ void finalize_total(const double* __restrict__ acc, float* __restrict__ total)
{
  if (threadIdx.x == 0 && blockIdx.x == 0) {
    double vq = 0.0, ent = 0.0;
    for (int si = 0; si < 6; ++si) {
      vq += acc[si * 18 + 0];
      double pse = acc[si * 18 + 1] / (double)BHW;
      double ce = 0.0;
      for (int cc = 0; cc < 16; ++cc) {
        double ap0 = acc[si * 18 + 2 + cc] / (double)BHW;
        double ap1 = 1.0 - ap0;
        ce -= ap0 * log(ap0 + 1e-5) + ap1 * log(ap1 + 1e-5);
      }
      ent += pse - ce;
    }
    *total = (float)(1.25 * vq / ((double)NELEM * 6.0) + (0.1 / 6.0) * ent);
  }
}

extern "C" void kernel_launch(void* const* d_in, const int* in_sizes, int n_in,
                              void* d_out, int out_size, void* d_ws, size_t ws_size,
                              hipStream_t stream)
{
  const float* f     = (const float*)d_in[0];
  const float* phi_w = (const float*)d_in[1];
  const float* phi_b = (const float*)d_in[2];
  float* out   = (float*)d_out;
  float* fhi   = out;                 // [0, NELEM) — fully overwritten
  float* total = out + NELEM;
  float* hist  = out + NELEM + 1;     // 6*65536
  double* acc  = (double*)d_ws;       // 108 doubles

  hipMemsetAsync((void*)(out + NELEM), 0, (size_t)(1 + 6 * VOCAB) * sizeof(float), stream);
  hipMemsetAsync(d_ws, 0, 1024, stream);

  lfq_all<<<256, 1024, 0, stream>>>(f, phi_w, phi_b, fhi, hist, acc);
  finalize_total<<<1, 64, 0, stream>>>(acc, total);
}

// Round 6
// 384.078 us; speedup vs baseline: 1.7452x; 1.0083x over previous
//
#include <hip/hip_runtime.h>

#define VOCAB 65536
#define NELEM 4194304      // 256*16*32*32
#define BHW   262144       // 256*1024

__device__ __forceinline__ double cubic_d(double t) {
  const double a = -0.75;
  t = fabs(t);
  if (t <= 1.0) return ((a + 2.0) * t - (a + 3.0)) * t * t + 1.0;
  if (t < 2.0)  return a * (((t - 5.0) * t + 8.0) * t - 4.0);
  return 0.0;
}

// PN=32 idx slot: XOR swizzle -> conflict-free for both writes (fixed y, varying x)
// and reads (fixed x, varying y). Bijective in (x,y).
__device__ __forceinline__ int idx32_slot(int x, int y) { return (x << 5) | ((y ^ x) & 31); }

// thread map (1024 threads): xq=t&7 (4-x strip, x0=4*xq), y=(t>>3)&31, g=t>>8
// owns channels 4g..4g+3. fhat[cc][k] = f_hat(c=4g+cc, y, x=4*xq+k) in f64.
template<int PN>
__device__ __forceinline__ void process_scale(
    int si, int phi_idx, bool load_w,
    const float* __restrict__ phi_w, const float* __restrict__ phi_b,
    float* __restrict__ hist, double* __restrict__ acc,
    const float (&fown)[4][4], double (&fhat)[4][4],
    double* __restrict__ hupd, float* __restrict__ wlds,
    unsigned* __restrict__ idxL, float* __restrict__ wMb, float* __restrict__ wMT,
    float* __restrict__ bias16, double* __restrict__ red,
    int t, int y, int g, int x0)
{
  constexpr int CELLS = PN * PN;
  constexpr int S = 32 / PN;

  // ---------- P0: zero idx, (re)load weights, wM, stage resid ----------
  idxL[t] = 0u;
  if (load_w) {
    for (int i = t; i < 2304; i += 1024) wlds[i] = phi_w[phi_idx * 2304 + i];
    if (t < 16) bias16[t] = phi_b[phi_idx * 16 + t];
  }
  if constexpr (PN != 32) {
    if (t < 32) {
      float wrow[PN];
      #pragma unroll
      for (int q = 0; q < PN; ++q) wrow[q] = 0.0f;
      double xp = ((double)t + 0.5) * (double)PN / 32.0 - 0.5;
      int q0 = (int)floor(xp);
      for (int k = 0; k < 4; ++k) {
        int j = q0 + k - 1;
        int jc = j < 0 ? 0 : (j > PN - 1 ? PN - 1 : j);
        wrow[jc] += (float)cubic_d(xp - (double)j);   // f32 accumulate == np M build
      }
      #pragma unroll
      for (int q = 0; q < PN; ++q) { wMb[t * PN + q] = wrow[q]; wMT[q * 32 + t] = wrow[q]; }
    }
    #pragma unroll
    for (int cc = 0; cc < 4; ++cc) {
      double* hp = hupd + (4 * g + cc) * 1056 + y * 33 + x0;
      #pragma unroll
      for (int k = 0; k < 4; ++k) hp[k] = (double)fown[cc][k] - fhat[cc][k];
    }
  }
  __syncthreads();

  // ---------- P2: quantize (sign of f64 cell sums) -> idxL ----------
  if constexpr (PN == 32) {
    #pragma unroll
    for (int k = 0; k < 4; ++k) {
      unsigned bb = 0;
      #pragma unroll
      for (int cc = 0; cc < 4; ++cc)
        if ((double)fown[cc][k] - fhat[cc][k] > 0.0) bb |= (1u << cc);
      if (bb) atomicOr(&idxL[idx32_slot(x0 + k, y)], bb << (4 * g));
    }
  } else if constexpr (PN == 16) {
    int cell = t & 255;
    int i0 = (cell >> 4) * 2, j0 = (cell & 15) * 2;
    unsigned bits = 0;
    #pragma unroll
    for (int k = 0; k < 4; ++k) {
      int c = (t >> 8) + 4 * k;
      const double* hp = hupd + c * 1056 + i0 * 33 + j0;
      double s = hp[0] + hp[1] + hp[33] + hp[34];
      if (s > 0.0) bits |= (1u << c);
    }
    atomicOr(&idxL[cell], bits);
  } else if constexpr (PN == 8) {
    int c = t >> 6, cell = t & 63;
    const double* hp = hupd + c * 1056 + ((cell >> 3) * 4) * 33 + (cell & 7) * 4;
    double s = 0.0;
    #pragma unroll
    for (int dy = 0; dy < 4; ++dy)
      #pragma unroll
      for (int dx = 0; dx < 4; ++dx) s += hp[dy * 33 + dx];
    if (s > 0.0) atomicOr(&idxL[cell], 1u << c);
  } else {   // PN 1,2,4
    constexpr int TASKS = 16 * CELLS;
    constexpr int G = 1024 / TASKS;       // 64, 16, 4
    int p = t / G, sub = t % G;
    int c = p / CELLS, cell = p % CELLS;
    const double* hp = hupd + c * 1056 + ((cell / PN) * S) * 33 + (cell % PN) * S;
    double s = 0.0;
    for (int e = sub; e < S * S; e += G) {
      int dy = e / S, dx = e % S;
      s += hp[dy * 33 + dx];
    }
    #pragma unroll
    for (int off = G / 2; off > 0; off >>= 1) s += __shfl_down(s, off, G);
    if (sub == 0 && s > 0.0) atomicOr(&idxL[cell], 1u << c);
  }
  __syncthreads();

  // ---------- P3: hist + upsample codes -> hupd ----------
  if constexpr (PN == 32) {
    atomicAdd(&hist[5 * VOCAB + idxL[t]], 1.0f);   // swizzle is bijective
  } else {
    if (t < CELLS) atomicAdd(&hist[(size_t)si * VOCAB + idxL[t]], 1.0f);
  }
  {
    int c2 = t >> 6, sub = (t >> 5) & 1, y2 = t & 31;
    double* hrow = hupd + c2 * 1056 + y2 * 33;
    if constexpr (PN == 32) {
      #pragma unroll
      for (int xi = 0; xi < 16; ++xi) {
        int x = 16 * sub + xi;
        hrow[x] = ((idxL[idx32_slot(x, y2)] >> c2) & 1) ? 1.0 : -1.0;
      }
    } else {
      double tmp[PN];
      #pragma unroll
      for (int q = 0; q < PN; ++q) tmp[q] = 0.0;
      #pragma unroll
      for (int r = 0; r < PN; ++r) {
        double w = (double)wMT[r * 32 + y2];
        #pragma unroll
        for (int q = 0; q < PN; ++q) {
          double sg = ((idxL[r * PN + q] >> c2) & 1) ? 1.0 : -1.0;
          tmp[q] = fma(w, sg, tmp[q]);
        }
      }
      #pragma unroll
      for (int xi = 0; xi < 16; ++xi) {
        int x = 16 * sub + xi;
        double s2 = 0.0;
        #pragma unroll
        for (int q = 0; q < PN; ++q) s2 = fma((double)wMb[x * PN + q], tmp[q], s2);
        hrow[x] = s2;
      }
    }
  }
  __syncthreads();

  // ---------- P4: conv3x3 (row-streamed, 6-wide halo) + phi mix + update + losses ----------
  double accv[4][4];
  #pragma unroll
  for (int cc = 0; cc < 4; ++cc)
    #pragma unroll
    for (int k = 0; k < 4; ++k) accv[cc][k] = 0.0;

  for (int ci = 0; ci < 16; ++ci) {
    const double* hbase = hupd + ci * 1056;
    #pragma unroll
    for (int dy = 0; dy < 3; ++dy) {
      int ry = y + dy - 1;
      if (ry < 0 || ry > 31) continue;
      double prow[6];
      const double* hr = hbase + ry * 33;
      #pragma unroll
      for (int jj = 0; jj < 6; ++jj) {
        int xx = x0 - 1 + jj;
        prow[jj] = (xx < 0 || xx > 31) ? 0.0 : hr[xx];
      }
      #pragma unroll
      for (int cc = 0; cc < 4; ++cc) {
        const float* wp = wlds + (((4 * g + cc) * 16 + ci) * 9 + dy * 3);
        double w0 = (double)wp[0], w1 = (double)wp[1], w2 = (double)wp[2];
        #pragma unroll
        for (int k = 0; k < 4; ++k)
          accv[cc][k] = fma(w0, prow[k], fma(w1, prow[k + 1], fma(w2, prow[k + 2], accv[cc][k])));
      }
    }
  }

  double mse = 0.0;
  float entf = 0.0f;
  float ps[4] = {0.0f, 0.0f, 0.0f, 0.0f};
  #pragma unroll
  for (int cc = 0; cc < 4; ++cc) {
    int c = 4 * g + cc;
    double bco = (double)bias16[c];
    const double* hu = hupd + c * 1056 + y * 33 + x0;
    float psl = 0.0f;
    #pragma unroll
    for (int k = 0; k < 4; ++k) {
      double h = 0.5 * hu[k] + 0.5 * (accv[cc][k] + bco);
      double fv = (double)fown[cc][k];
      double xr = fv - fhat[cc][k];            // residual BEFORE update
      double fn = fhat[cc][k] + h;
      fhat[cc][k] = fn;
      double d = fn - fv;
      mse += d * d;
      float pr = 1.0f / (1.0f + __expf(400.0f * (float)xr));   // sigmoid(-400 x)
      entf -= pr * __logf(pr + 1e-5f) + (1.0f - pr) * __logf(1.0f - pr + 1e-5f);
      psl += pr;
    }
    ps[cc] = psl;
  }
  double ent_d = (double)entf;
  #pragma unroll
  for (int off = 32; off > 0; off >>= 1) {
    mse   += __shfl_down(mse, off);
    ent_d += __shfl_down(ent_d, off);
    ps[0] += __shfl_down(ps[0], off);
    ps[1] += __shfl_down(ps[1], off);
    ps[2] += __shfl_down(ps[2], off);
    ps[3] += __shfl_down(ps[3], off);
  }
  int w = t >> 6;
  if ((t & 63) == 0) {
    red[w * 6 + 0] = mse;
    red[w * 6 + 1] = ent_d;
    red[w * 6 + 2] = (double)ps[0];
    red[w * 6 + 3] = (double)ps[1];
    red[w * 6 + 4] = (double)ps[2];
    red[w * 6 + 5] = (double)ps[3];
  }
  __syncthreads();

  // ---------- P5: block totals -> global acc ----------
  if (t == 0) {
    double m = 0.0, e = 0.0;
    #pragma unroll
    for (int ww = 0; ww < 16; ++ww) { m += red[ww * 6]; e += red[ww * 6 + 1]; }
    atomicAdd(&acc[si * 18 + 0], m);
    atomicAdd(&acc[si * 18 + 1], e);
  }
  if (t < 16) {
    // channel t = 4*gg + cc is produced by waves 4*gg .. 4*gg+3 (4 waves per g)
    int gg = t >> 2, cc = t & 3;
    double p = red[(4 * gg + 0) * 6 + 2 + cc] + red[(4 * gg + 1) * 6 + 2 + cc]
             + red[(4 * gg + 2) * 6 + 2 + cc] + red[(4 * gg + 3) * 6 + 2 + cc];
    atomicAdd(&acc[si * 18 + 2 + t], p);
  }
  __syncthreads();
}

// Pin exactly 4 waves/EU (our 1024-thread block = 16 waves = 4/SIMD, LDS forces
// 1 block/CU) so the allocator budgets 512/4 = 128 VGPRs instead of the 64 its
// default occupancy heuristic picked (which spilled ~280 MB to scratch).
__global__ void
__attribute__((amdgpu_flat_work_group_size(1024, 1024), amdgpu_waves_per_eu(4, 4)))
lfq_all(
    const float* __restrict__ f, const float* __restrict__ phi_w,
    const float* __restrict__ phi_b, float* __restrict__ fhi,
    float* __restrict__ hist, double* __restrict__ acc)
{
  __shared__ double   hupd[16 * 1056];   // 135168 B: resid / upsampled codes
  __shared__ float    wlds[2304];        // conv weights
  __shared__ unsigned idxL[1024];        // codes per cell (XOR-swizzled for PN=32)
  __shared__ float    wMb[512];          // bicubic M [32][PN]
  __shared__ float    wMT[512];          // transposed [PN][32]
  __shared__ float    bias16[16];
  __shared__ double   red[96];           // 16 waves x 6 slots

  const int t = threadIdx.x;
  const int xq = t & 7, y = (t >> 3) & 31, g = t >> 8;
  const int x0 = xq * 4;
  const size_t ibase = (size_t)blockIdx.x * 16384;

  float fown[4][4];
  double fhat[4][4];
  #pragma unroll
  for (int cc = 0; cc < 4; ++cc) {
    const float* fp = f + ibase + (size_t)(4 * g + cc) * 1024 + y * 32 + x0;
    #pragma unroll
    for (int k = 0; k < 4; ++k) { fown[cc][k] = fp[k]; fhat[cc][k] = 0.0; }
  }

  // PHI_IDX = [0,0,1,2,3,3]
  process_scale<1 >(0, 0, true,  phi_w, phi_b, hist, acc, fown, fhat, hupd, wlds, idxL, wMb, wMT, bias16, red, t, y, g, x0);
  process_scale<2 >(1, 0, false, phi_w, phi_b, hist, acc, fown, fhat, hupd, wlds, idxL, wMb, wMT, bias16, red, t, y, g, x0);
  process_scale<4 >(2, 1, true,  phi_w, phi_b, hist, acc, fown, fhat, hupd, wlds, idxL, wMb, wMT, bias16, red, t, y, g, x0);
  process_scale<8 >(3, 2, true,  phi_w, phi_b, hist, acc, fown, fhat, hupd, wlds, idxL, wMb, wMT, bias16, red, t, y, g, x0);
  process_scale<16>(4, 3, true,  phi_w, phi_b, hist, acc, fown, fhat, hupd, wlds, idxL, wMb, wMT, bias16, red, t, y, g, x0);
  process_scale<32>(5, 3, false, phi_w, phi_b, hist, acc, fown, fhat, hupd, wlds, idxL, wMb, wMT, bias16, red, t, y, g, x0);

  #pragma unroll
  for (int cc = 0; cc < 4; ++cc) {
    float* op = fhi + ibase + (size_t)(4 * g + cc) * 1024 + y * 32 + x0;
    #pragma unroll
    for (int k = 0; k < 4; ++k) op[k] = (float)fhat[cc][k];
  }
}

__global__ void finalize_total(const double* __restrict__ acc, float* __restrict__ total)
{
  if (threadIdx.x == 0 && blockIdx.x == 0) {
    double vq = 0.0, ent = 0.0;
    for (int si = 0; si < 6; ++si) {
      vq += acc[si * 18 + 0];
      double pse = acc[si * 18 + 1] / (double)BHW;
      double ce = 0.0;
      for (int cc = 0; cc < 16; ++cc) {
        double ap0 = acc[si * 18 + 2 + cc] / (double)BHW;
        double ap1 = 1.0 - ap0;
        ce -= ap0 * log(ap0 + 1e-5) + ap1 * log(ap1 + 1e-5);
      }
      ent += pse - ce;
    }
    *total = (float)(1.25 * vq / ((double)NELEM * 6.0) + (0.1 / 6.0) * ent);
  }
}

extern "C" void kernel_launch(void* const* d_in, const int* in_sizes, int n_in,
                              void* d_out, int out_size, void* d_ws, size_t ws_size,
                              hipStream_t stream)
{
  const float* f     = (const float*)d_in[0];
  const float* phi_w = (const float*)d_in[1];
  const float* phi_b = (const float*)d_in[2];
  float* out   = (float*)d_out;
  float* fhi   = out;                 // [0, NELEM) — fully overwritten
  float* total = out + NELEM;
  float* hist  = out + NELEM + 1;     // 6*65536
  double* acc  = (double*)d_ws;       // 108 doubles

  hipMemsetAsync((void*)(out + NELEM), 0, (size_t)(1 + 6 * VOCAB) * sizeof(float), stream);
  hipMemsetAsync(d_ws, 0, 1024, stream);

  lfq_all<<<256, 1024, 0, stream>>>(f, phi_w, phi_b, fhi, hist, acc);
  finalize_total<<<1, 64, 0, stream>>>(acc, total);
}